// Round 3
// baseline (1007.290 us; speedup 1.0000x reference)
//
#include <hip/hip_runtime.h>
#include <hip/hip_bf16.h>
#include <stdint.h>

#define NN 100000
#define NE 1600000
#define DD 128
#define HH 256
#define LL 40

typedef __attribute__((ext_vector_type(8))) short short8;
typedef __attribute__((ext_vector_type(4))) float float4v;
typedef __attribute__((ext_vector_type(8))) float float8v;

__device__ __forceinline__ float bf2f(uint16_t u){ union{uint32_t i;float f;}v; v.i=((uint32_t)u)<<16; return v.f; }
__device__ __forceinline__ uint16_t f2bf(float f){
  union{float f;uint32_t i;}v; v.f=f; uint32_t u=v.i;
  u += 0x7FFFu + ((u>>16)&1u); return (uint16_t)(u>>16);
}
// split f32 into hi+lo bf16 (lo = residual), ~16-bit effective mantissa
__device__ __forceinline__ void split2(float f, short &hi, short &lo){
  uint16_t h = f2bf(f);
  hi = (short)h;
  lo = (short)f2bf(f - bf2f(h));
}

// ---------------- preprocessing ----------------

__global__ __launch_bounds__(256) void count_edges(const int* __restrict__ row, int* __restrict__ counts){
  int e = blockIdx.x*256 + threadIdx.x;
  if (e < NE) atomicAdd(&counts[row[e]], 1);
}

__global__ __launch_bounds__(256) void scan_partial(const int* __restrict__ counts,
                                                    int* __restrict__ offs, int* __restrict__ bsums){
  __shared__ int sh[256];
  int t = threadIdx.x, i = blockIdx.x*256 + t;
  int v = (i < NN) ? counts[i] : 0;
  sh[t] = v; __syncthreads();
  for (int d = 1; d < 256; d <<= 1){
    int x = (t >= d) ? sh[t-d] : 0;
    __syncthreads();
    sh[t] += x;
    __syncthreads();
  }
  if (i < NN) offs[i] = sh[t] - v;
  if (t == 255) bsums[blockIdx.x] = sh[255];
}

__global__ __launch_bounds__(512) void scan_block(int* __restrict__ bsums, int nb){
  __shared__ int sh[512];
  int t = threadIdx.x;
  int v = (t < nb) ? bsums[t] : 0;
  sh[t] = v; __syncthreads();
  for (int d = 1; d < 512; d <<= 1){
    int x = (t >= d) ? sh[t-d] : 0;
    __syncthreads();
    sh[t] += x;
    __syncthreads();
  }
  if (t < nb) bsums[t] = sh[t] - v;
}

__global__ __launch_bounds__(256) void scan_add(int* __restrict__ offs, const int* __restrict__ bsums,
                                                int* __restrict__ cursor){
  int i = blockIdx.x*256 + threadIdx.x;
  if (i < NN){
    int v = offs[i] + bsums[blockIdx.x];
    offs[i] = v;
    cursor[i] = v;
  }
  if (i == 0) offs[NN] = NE;
}

__global__ __launch_bounds__(256) void compute_dinv(const int* __restrict__ counts, float* __restrict__ dinv){
  int i = blockIdx.x*256 + threadIdx.x;
  if (i < NN) dinv[i] = rsqrtf((float)(counts[i] + 1));
}

__global__ __launch_bounds__(256) void fill_csr(const int* __restrict__ row, const int* __restrict__ col,
                                                int* __restrict__ cursor, int* __restrict__ csr_col){
  int e = blockIdx.x*256 + threadIdx.x;
  if (e < NE){
    int r = row[e];
    int p = atomicAdd(&cursor[r], 1);
    csr_col[p] = col[e];
  }
}

// ---------------- weight pre-swizzle (f32 -> hi/lo bf16 B-fragments) ----------------
// Wf[frag(kb,nt)*512 + lane*8 + j] = W[k = kb*32 + (lane>>4)*8 + j][n = nt*16 + (lane&15)]

template<int KDIM, int NCOL, int NTBP>
__global__ __launch_bounds__(256) void swz(const float* __restrict__ W,
                                           uint16_t* __restrict__ Whi, uint16_t* __restrict__ Wlo){
  constexpr int KB = KDIM / 32;
  constexpr int TOT = KB * NTBP * 512;
  int idx = blockIdx.x*256 + threadIdx.x;
  if (idx >= TOT) return;
  int frag = idx >> 9, r = idx & 511, ln = r >> 3, j = r & 7;
  int kb = frag / NTBP, nt = frag - kb*NTBP;
  int k = kb*32 + ((ln >> 4) << 3) + j;
  int n = nt*16 + (ln & 15);
  float w = (n < NCOL) ? W[k*NCOL + n] : 0.f;
  short h, l; split2(w, h, l);
  Whi[idx] = (uint16_t)h; Wlo[idx] = (uint16_t)l;
}

// ---------------- aggregation (pure f32): one wave per row ----------------
// agg[r] = dinv[r] * ( sum_{c in adj(r)} dinv[c]*h[c] + dinv[r]*h[r] )

__global__ __launch_bounds__(256) void agg_f32(const float2* __restrict__ hin,
                                               const int* __restrict__ offs,
                                               const int* __restrict__ csr_col,
                                               const float* __restrict__ dinv,
                                               float2* __restrict__ outp){
  const int w = (blockIdx.x*256 + threadIdx.x) >> 6;
  const int lane = threadIdx.x & 63;
  if (w >= NN) return;
  const int s = offs[w], e = offs[w+1];
  float a0 = 0.f, a1 = 0.f;
  for (int i = s; i < e; ++i){
    int c = csr_col[i];
    float wt = dinv[c];
    float2 v = hin[(size_t)c*64 + lane];
    a0 += wt * v.x;
    a1 += wt * v.y;
  }
  float dr = dinv[w];
  float2 v = hin[(size_t)w*64 + lane];
  a0 = (a0 + dr * v.x) * dr;
  a1 = (a1 + dr * v.y) * dr;
  outp[(size_t)w*64 + lane] = make_float2(a0, a1);
}

// ---------------- square GEMM in place: A <- relu(A @ W + b), A[M,128] f32 ----------------
// 3-term hi/lo split: acc = Ahi*Whi + Alo*Whi + Ahi*Wlo  (~2^-16 rel precision).
// Wave reads only its own 16 rows (all reads precede writes in program order).
// A-frag: A[m=m0+(lane&15)][k=kb*32+(lane>>4)*8+j]; C/D: col=lane&15, row=(lane>>4)*4+reg.

__global__ __launch_bounds__(256) void gemm_ip(float* __restrict__ A,
                                               const uint16_t* __restrict__ Whi,
                                               const uint16_t* __restrict__ Wlo,
                                               const float* __restrict__ bias, int M){
  const int lane = threadIdx.x & 63;
  const int wid = threadIdx.x >> 6;
  const int m0 = (blockIdx.x*4 + wid)*16;
  if (m0 >= M) return;
  const int am = m0 + (lane & 15);
  const int amc = (am < M) ? am : (M - 1);

  float4v acc[8];
#pragma unroll
  for (int nt = 0; nt < 8; ++nt){ float4v z = {0.f,0.f,0.f,0.f}; acc[nt] = z; }

#pragma unroll
  for (int kb = 0; kb < 4; ++kb){
    float8v a = *(const float8v*)&A[(size_t)amc*128 + kb*32 + ((lane >> 4) << 3)];
    short8 ahi, alo;
#pragma unroll
    for (int j = 0; j < 8; ++j){ short h, l; split2(a[j], h, l); ahi[j] = h; alo[j] = l; }
#pragma unroll
    for (int nt = 0; nt < 8; ++nt){
      short8 bh = *(const short8*)&Whi[(kb*8 + nt)*512 + lane*8];
      short8 bl = *(const short8*)&Wlo[(kb*8 + nt)*512 + lane*8];
      acc[nt] = __builtin_amdgcn_mfma_f32_16x16x32_bf16(ahi, bh, acc[nt], 0, 0, 0);
      acc[nt] = __builtin_amdgcn_mfma_f32_16x16x32_bf16(alo, bh, acc[nt], 0, 0, 0);
      acc[nt] = __builtin_amdgcn_mfma_f32_16x16x32_bf16(ahi, bl, acc[nt], 0, 0, 0);
    }
  }

  const int col = lane & 15;
  const int rb  = (lane >> 4) * 4;
#pragma unroll
  for (int nt = 0; nt < 8; ++nt){
    int n = nt*16 + col;
    float bv = bias[n];
#pragma unroll
    for (int r = 0; r < 4; ++r){
      int m = m0 + rb + r;
      if (m < M){
        float v = acc[nt][r] + bv;
        A[(size_t)m*128 + n] = v > 0.f ? v : 0.f;
      }
    }
  }
}

// ---------------- fused MLP: out = (relu(A @ Wm1 + bm1)) @ Wm2 + bm2 (f32 in/out) ----------------
// Hidden 64x256 tile as hi/lo bf16 in LDS (stride 264 -> 2-way bank alias only, free).

__global__ __launch_bounds__(256) void mlp_fused(const float* __restrict__ A,
                                                 const uint16_t* __restrict__ W1hi,
                                                 const uint16_t* __restrict__ W1lo,
                                                 const float* __restrict__ b1,
                                                 const uint16_t* __restrict__ W2hi,
                                                 const uint16_t* __restrict__ W2lo,
                                                 const float* __restrict__ b2,
                                                 float* __restrict__ out, int M){
  __shared__ uint16_t hidh[64*264];
  __shared__ uint16_t hidl[64*264];
  const int lane = threadIdx.x & 63;
  const int wid = threadIdx.x >> 6;
  const int m0 = (blockIdx.x*4 + wid)*16;
  const int am = m0 + (lane & 15);
  const int amc = (am < M) ? am : (M - 1);
  const int col = lane & 15;
  const int rb  = (lane >> 4) * 4;

  // phase 1: hidden = relu(A @ Wm1 + bm1), K=128, N=256
  float4v acc1[16];
#pragma unroll
  for (int nt = 0; nt < 16; ++nt){ float4v z = {0.f,0.f,0.f,0.f}; acc1[nt] = z; }
#pragma unroll
  for (int kb = 0; kb < 4; ++kb){
    float8v a = *(const float8v*)&A[(size_t)amc*128 + kb*32 + ((lane >> 4) << 3)];
    short8 ahi, alo;
#pragma unroll
    for (int j = 0; j < 8; ++j){ short h, l; split2(a[j], h, l); ahi[j] = h; alo[j] = l; }
#pragma unroll
    for (int nt = 0; nt < 16; ++nt){
      short8 bh = *(const short8*)&W1hi[(kb*16 + nt)*512 + lane*8];
      short8 bl = *(const short8*)&W1lo[(kb*16 + nt)*512 + lane*8];
      acc1[nt] = __builtin_amdgcn_mfma_f32_16x16x32_bf16(ahi, bh, acc1[nt], 0, 0, 0);
      acc1[nt] = __builtin_amdgcn_mfma_f32_16x16x32_bf16(alo, bh, acc1[nt], 0, 0, 0);
      acc1[nt] = __builtin_amdgcn_mfma_f32_16x16x32_bf16(ahi, bl, acc1[nt], 0, 0, 0);
    }
  }
#pragma unroll
  for (int nt = 0; nt < 16; ++nt){
    float bv = b1[nt*16 + col];
#pragma unroll
    for (int r = 0; r < 4; ++r){
      float v = acc1[nt][r] + bv;
      v = v > 0.f ? v : 0.f;
      short h, l; split2(v, h, l);
      hidh[(wid*16 + rb + r)*264 + nt*16 + col] = (uint16_t)h;
      hidl[(wid*16 + rb + r)*264 + nt*16 + col] = (uint16_t)l;
    }
  }
  __syncthreads();

  // phase 2: out = hidden @ Wm2 + bm2, K=256, N=40 (padded to 48)
  float4v acc2[3];
#pragma unroll
  for (int nt = 0; nt < 3; ++nt){ float4v z = {0.f,0.f,0.f,0.f}; acc2[nt] = z; }
#pragma unroll
  for (int kb = 0; kb < 8; ++kb){
    int ho = (wid*16 + (lane & 15))*264 + kb*32 + ((lane >> 4) << 3);
    short8 ahi = *(const short8*)&hidh[ho];
    short8 alo = *(const short8*)&hidl[ho];
#pragma unroll
    for (int nt = 0; nt < 3; ++nt){
      short8 bh = *(const short8*)&W2hi[(kb*3 + nt)*512 + lane*8];
      short8 bl = *(const short8*)&W2lo[(kb*3 + nt)*512 + lane*8];
      acc2[nt] = __builtin_amdgcn_mfma_f32_16x16x32_bf16(ahi, bh, acc2[nt], 0, 0, 0);
      acc2[nt] = __builtin_amdgcn_mfma_f32_16x16x32_bf16(alo, bh, acc2[nt], 0, 0, 0);
      acc2[nt] = __builtin_amdgcn_mfma_f32_16x16x32_bf16(ahi, bl, acc2[nt], 0, 0, 0);
    }
  }
#pragma unroll
  for (int nt = 0; nt < 3; ++nt){
    int n = nt*16 + col;
    if (n < LL){
      float bv = b2[n];
#pragma unroll
      for (int r = 0; r < 4; ++r){
        int m = m0 + rb + r;
        if (m < M) out[(size_t)m*LL + n] = acc2[nt][r] + bv;
      }
    }
  }
}

// ---------------- launch ----------------

extern "C" void kernel_launch(void* const* d_in, const int* in_sizes, int n_in,
                              void* d_out, int out_size, void* d_ws, size_t ws_size,
                              hipStream_t stream){
  const float* x   = (const float*)d_in[0];
  const int*   ei  = (const int*)d_in[1];
  const float* W0  = (const float*)d_in[2];
  const float* b0  = (const float*)d_in[3];
  const float* W1  = (const float*)d_in[4];
  const float* b1  = (const float*)d_in[5];
  const float* W2  = (const float*)d_in[6];
  const float* b2  = (const float*)d_in[7];
  const float* Wm1 = (const float*)d_in[8];
  const float* bm1 = (const float*)d_in[9];
  const float* Wm2 = (const float*)d_in[10];
  const float* bm2 = (const float*)d_in[11];
  const int* row = ei;        // edge_index[0]
  const int* col = ei + NE;   // edge_index[1]

  char* ws = (char*)d_ws;
  size_t off = 0;
  auto alloc = [&](size_t bytes)->void*{
    void* p = ws + off;
    off += (bytes + 255) & ~(size_t)255;
    return p;
  };
  int*      counts  = (int*)alloc((size_t)NN*4);
  int*      offs    = (int*)alloc(((size_t)NN+1)*4);
  int*      cursor  = (int*)alloc((size_t)NN*4);
  int*      bsums   = (int*)alloc(1024*4);
  float*    dinv    = (float*)alloc((size_t)NN*4);
  int*      csr_col = (int*)alloc((size_t)NE*4);
  uint16_t* W0hi    = (uint16_t*)alloc(4*8*512*2);
  uint16_t* W0lo    = (uint16_t*)alloc(4*8*512*2);
  uint16_t* W1hi    = (uint16_t*)alloc(4*8*512*2);
  uint16_t* W1lo    = (uint16_t*)alloc(4*8*512*2);
  uint16_t* W2hi    = (uint16_t*)alloc(4*8*512*2);
  uint16_t* W2lo    = (uint16_t*)alloc(4*8*512*2);
  uint16_t* Wm1hi   = (uint16_t*)alloc(4*16*512*2);
  uint16_t* Wm1lo   = (uint16_t*)alloc(4*16*512*2);
  uint16_t* Wm2hi   = (uint16_t*)alloc(8*3*512*2);
  uint16_t* Wm2lo   = (uint16_t*)alloc(8*3*512*2);
  float*    HA      = (float*)alloc((size_t)NN*DD*4);
  float*    HB      = (float*)alloc((size_t)NN*DD*4);
  // total ~110.9 MB

  hipMemsetAsync(counts, 0, (size_t)NN*4, stream);
  count_edges<<<(NE+255)/256, 256, 0, stream>>>(row, counts);
  const int NB = (NN+255)/256;
  scan_partial<<<NB, 256, 0, stream>>>(counts, offs, bsums);
  scan_block<<<1, 512, 0, stream>>>(bsums, NB);
  scan_add<<<NB, 256, 0, stream>>>(offs, bsums, cursor);
  compute_dinv<<<(NN+255)/256, 256, 0, stream>>>(counts, dinv);
  fill_csr<<<(NE+255)/256, 256, 0, stream>>>(row, col, cursor, csr_col);

  swz<128,128,8><<<(4*8*512+255)/256, 256, 0, stream>>>(W0, W0hi, W0lo);
  swz<128,128,8><<<(4*8*512+255)/256, 256, 0, stream>>>(W1, W1hi, W1lo);
  swz<128,128,8><<<(4*8*512+255)/256, 256, 0, stream>>>(W2, W2hi, W2lo);
  swz<128,256,16><<<(4*16*512+255)/256, 256, 0, stream>>>(Wm1, Wm1hi, Wm1lo);
  swz<256,40,3><<<(8*3*512+255)/256, 256, 0, stream>>>(Wm2, Wm2hi, Wm2lo);

  const int AGG_BLOCKS = (NN*64 + 255)/256;
  const int GB = (NN + 63)/64;

  agg_f32<<<AGG_BLOCKS, 256, 0, stream>>>((const float2*)x, offs, csr_col, dinv, (float2*)HB);
  gemm_ip<<<GB, 256, 0, stream>>>(HB, W0hi, W0lo, b0, NN);

  agg_f32<<<AGG_BLOCKS, 256, 0, stream>>>((const float2*)HB, offs, csr_col, dinv, (float2*)HA);
  gemm_ip<<<GB, 256, 0, stream>>>(HA, W1hi, W1lo, b1, NN);

  agg_f32<<<AGG_BLOCKS, 256, 0, stream>>>((const float2*)HA, offs, csr_col, dinv, (float2*)HB);
  gemm_ip<<<GB, 256, 0, stream>>>(HB, W2hi, W2lo, b2, NN);

  mlp_fused<<<GB, 256, 0, stream>>>(HB, Wm1hi, Wm1lo, bm1, Wm2hi, Wm2lo, bm2, (float*)d_out, NN);
}

// Round 4
// 838.642 us; speedup vs baseline: 1.2011x; 1.2011x over previous
//
#include <hip/hip_runtime.h>
#include <hip/hip_bf16.h>
#include <stdint.h>

#define NN 100000
#define NE 1600000
#define DD 128
#define HH 256
#define LL 40

typedef __attribute__((ext_vector_type(8))) short short8;
typedef __attribute__((ext_vector_type(4))) float float4v;
typedef __attribute__((ext_vector_type(8))) float float8v;

__device__ __forceinline__ float bf2f(uint16_t u){ union{uint32_t i;float f;}v; v.i=((uint32_t)u)<<16; return v.f; }
__device__ __forceinline__ uint16_t f2bf(float f){
  union{float f;uint32_t i;}v; v.f=f; uint32_t u=v.i;
  u += 0x7FFFu + ((u>>16)&1u); return (uint16_t)(u>>16);
}
// split f32 into hi+lo bf16 (lo = residual), ~16-bit effective mantissa
__device__ __forceinline__ void split2(float f, short &hi, short &lo){
  uint16_t h = f2bf(f);
  hi = (short)h;
  lo = (short)f2bf(f - bf2f(h));
}

// ---------------- preprocessing ----------------

__global__ __launch_bounds__(256) void count_edges(const int* __restrict__ row, int* __restrict__ counts){
  int e = blockIdx.x*256 + threadIdx.x;
  if (e < NE) atomicAdd(&counts[row[e]], 1);
}

__global__ __launch_bounds__(256) void scan_partial(const int* __restrict__ counts,
                                                    int* __restrict__ offs, int* __restrict__ bsums){
  __shared__ int sh[256];
  int t = threadIdx.x, i = blockIdx.x*256 + t;
  int v = (i < NN) ? counts[i] : 0;
  sh[t] = v; __syncthreads();
  for (int d = 1; d < 256; d <<= 1){
    int x = (t >= d) ? sh[t-d] : 0;
    __syncthreads();
    sh[t] += x;
    __syncthreads();
  }
  if (i < NN) offs[i] = sh[t] - v;
  if (t == 255) bsums[blockIdx.x] = sh[255];
}

__global__ __launch_bounds__(512) void scan_block(int* __restrict__ bsums, int nb){
  __shared__ int sh[512];
  int t = threadIdx.x;
  int v = (t < nb) ? bsums[t] : 0;
  sh[t] = v; __syncthreads();
  for (int d = 1; d < 512; d <<= 1){
    int x = (t >= d) ? sh[t-d] : 0;
    __syncthreads();
    sh[t] += x;
    __syncthreads();
  }
  if (t < nb) bsums[t] = sh[t] - v;
}

__global__ __launch_bounds__(256) void scan_add(int* __restrict__ offs, const int* __restrict__ bsums,
                                                int* __restrict__ cursor){
  int i = blockIdx.x*256 + threadIdx.x;
  if (i < NN){
    int v = offs[i] + bsums[blockIdx.x];
    offs[i] = v;
    cursor[i] = v;
  }
  if (i == 0) offs[NN] = NE;
}

__global__ __launch_bounds__(256) void compute_dinv(const int* __restrict__ counts, float* __restrict__ dinv){
  int i = blockIdx.x*256 + threadIdx.x;
  if (i < NN) dinv[i] = rsqrtf((float)(counts[i] + 1));
}

// also stores the per-edge normalization weight dinv[col] so the agg inner
// loop reads two sequential streams instead of doing a dependent random gather
__global__ __launch_bounds__(256) void fill_csr(const int* __restrict__ row, const int* __restrict__ col,
                                                const float* __restrict__ dinv,
                                                int* __restrict__ cursor,
                                                int* __restrict__ csr_col, float* __restrict__ csr_w){
  int e = blockIdx.x*256 + threadIdx.x;
  if (e < NE){
    int r = row[e];
    int c = col[e];
    int p = atomicAdd(&cursor[r], 1);
    csr_col[p] = c;
    csr_w[p] = dinv[c];
  }
}

// ---------------- weight pre-swizzle (f32 -> hi/lo bf16 B-fragments) ----------------

template<int KDIM, int NCOL, int NTBP>
__global__ __launch_bounds__(256) void swz(const float* __restrict__ W,
                                           uint16_t* __restrict__ Whi, uint16_t* __restrict__ Wlo){
  constexpr int KB = KDIM / 32;
  constexpr int TOT = KB * NTBP * 512;
  int idx = blockIdx.x*256 + threadIdx.x;
  if (idx >= TOT) return;
  int frag = idx >> 9, r = idx & 511, ln = r >> 3, j = r & 7;
  int kb = frag / NTBP, nt = frag - kb*NTBP;
  int k = kb*32 + ((ln >> 4) << 3) + j;
  int n = nt*16 + (ln & 15);
  float w = (n < NCOL) ? W[k*NCOL + n] : 0.f;
  short h, l; split2(w, h, l);
  Whi[idx] = (uint16_t)h; Wlo[idx] = (uint16_t)l;
}

// ---------------- aggregation (pure f32): one wave per row, 4-deep MLP ----------------
// agg[r] = dinv[r] * ( sum_{c in adj(r)} dinv[c]*h[c] + dinv[r]*h[r] )

__global__ __launch_bounds__(256) void agg_f32(const float2* __restrict__ hin,
                                               const int* __restrict__ offs,
                                               const int* __restrict__ csr_col,
                                               const float* __restrict__ csr_w,
                                               const float* __restrict__ dinv,
                                               float2* __restrict__ outp){
  const int w = (blockIdx.x*256 + threadIdx.x) >> 6;
  const int lane = threadIdx.x & 63;
  if (w >= NN) return;
  const int s = offs[w], e = offs[w+1];
  const float dr = dinv[w];
  const float2 vs = hin[(size_t)w*64 + lane];   // self-loop row, issued early

  float a0=0.f,a1=0.f,b0=0.f,b1=0.f,c0=0.f,c1=0.f,d0=0.f,d1=0.f;
  int i = s;
  for (; i + 4 <= e; i += 4){
    int j0 = csr_col[i],   j1 = csr_col[i+1], j2 = csr_col[i+2], j3 = csr_col[i+3];
    float w0 = csr_w[i],   w1 = csr_w[i+1],   w2 = csr_w[i+2],   w3 = csr_w[i+3];
    float2 v0 = hin[(size_t)j0*64 + lane];
    float2 v1 = hin[(size_t)j1*64 + lane];
    float2 v2 = hin[(size_t)j2*64 + lane];
    float2 v3 = hin[(size_t)j3*64 + lane];
    a0 += w0*v0.x; a1 += w0*v0.y;
    b0 += w1*v1.x; b1 += w1*v1.y;
    c0 += w2*v2.x; c1 += w2*v2.y;
    d0 += w3*v3.x; d1 += w3*v3.y;
  }
  for (; i < e; ++i){
    int c = csr_col[i]; float wt = csr_w[i];
    float2 v = hin[(size_t)c*64 + lane];
    a0 += wt*v.x; a1 += wt*v.y;
  }
  float r0 = ((a0 + b0) + (c0 + d0)) + dr*vs.x;
  float r1 = ((a1 + b1) + (c1 + d1)) + dr*vs.y;
  outp[(size_t)w*64 + lane] = make_float2(r0*dr, r1*dr);
}

// ---------------- square GEMM in place: A <- relu(A @ W + b), A[M,128] f32 ----------------
// 3-term hi/lo split: acc = Ahi*Whi + Alo*Whi + Ahi*Wlo  (~2^-16 rel precision).

__global__ __launch_bounds__(256) void gemm_ip(float* __restrict__ A,
                                               const uint16_t* __restrict__ Whi,
                                               const uint16_t* __restrict__ Wlo,
                                               const float* __restrict__ bias, int M){
  const int lane = threadIdx.x & 63;
  const int wid = threadIdx.x >> 6;
  const int m0 = (blockIdx.x*4 + wid)*16;
  if (m0 >= M) return;
  const int am = m0 + (lane & 15);
  const int amc = (am < M) ? am : (M - 1);

  float4v acc[8];
#pragma unroll
  for (int nt = 0; nt < 8; ++nt){ float4v z = {0.f,0.f,0.f,0.f}; acc[nt] = z; }

#pragma unroll
  for (int kb = 0; kb < 4; ++kb){
    float8v a = *(const float8v*)&A[(size_t)amc*128 + kb*32 + ((lane >> 4) << 3)];
    short8 ahi, alo;
#pragma unroll
    for (int j = 0; j < 8; ++j){ short h, l; split2(a[j], h, l); ahi[j] = h; alo[j] = l; }
#pragma unroll
    for (int nt = 0; nt < 8; ++nt){
      short8 bh = *(const short8*)&Whi[(kb*8 + nt)*512 + lane*8];
      short8 bl = *(const short8*)&Wlo[(kb*8 + nt)*512 + lane*8];
      acc[nt] = __builtin_amdgcn_mfma_f32_16x16x32_bf16(ahi, bh, acc[nt], 0, 0, 0);
      acc[nt] = __builtin_amdgcn_mfma_f32_16x16x32_bf16(alo, bh, acc[nt], 0, 0, 0);
      acc[nt] = __builtin_amdgcn_mfma_f32_16x16x32_bf16(ahi, bl, acc[nt], 0, 0, 0);
    }
  }

  const int col = lane & 15;
  const int rb  = (lane >> 4) * 4;
#pragma unroll
  for (int nt = 0; nt < 8; ++nt){
    int n = nt*16 + col;
    float bv = bias[n];
#pragma unroll
    for (int r = 0; r < 4; ++r){
      int m = m0 + rb + r;
      if (m < M){
        float v = acc[nt][r] + bv;
        A[(size_t)m*128 + n] = v > 0.f ? v : 0.f;
      }
    }
  }
}

// ---------------- fused MLP: out = (relu(A @ Wm1 + bm1)) @ Wm2 + bm2 (f32 in/out) ----------------

__global__ __launch_bounds__(256) void mlp_fused(const float* __restrict__ A,
                                                 const uint16_t* __restrict__ W1hi,
                                                 const uint16_t* __restrict__ W1lo,
                                                 const float* __restrict__ b1,
                                                 const uint16_t* __restrict__ W2hi,
                                                 const uint16_t* __restrict__ W2lo,
                                                 const float* __restrict__ b2,
                                                 float* __restrict__ out, int M){
  __shared__ uint16_t hidh[64*264];
  __shared__ uint16_t hidl[64*264];
  const int lane = threadIdx.x & 63;
  const int wid = threadIdx.x >> 6;
  const int m0 = (blockIdx.x*4 + wid)*16;
  const int am = m0 + (lane & 15);
  const int amc = (am < M) ? am : (M - 1);
  const int col = lane & 15;
  const int rb  = (lane >> 4) * 4;

  // phase 1: hidden = relu(A @ Wm1 + bm1), K=128, N=256
  float4v acc1[16];
#pragma unroll
  for (int nt = 0; nt < 16; ++nt){ float4v z = {0.f,0.f,0.f,0.f}; acc1[nt] = z; }
#pragma unroll
  for (int kb = 0; kb < 4; ++kb){
    float8v a = *(const float8v*)&A[(size_t)amc*128 + kb*32 + ((lane >> 4) << 3)];
    short8 ahi, alo;
#pragma unroll
    for (int j = 0; j < 8; ++j){ short h, l; split2(a[j], h, l); ahi[j] = h; alo[j] = l; }
#pragma unroll
    for (int nt = 0; nt < 16; ++nt){
      short8 bh = *(const short8*)&W1hi[(kb*16 + nt)*512 + lane*8];
      short8 bl = *(const short8*)&W1lo[(kb*16 + nt)*512 + lane*8];
      acc1[nt] = __builtin_amdgcn_mfma_f32_16x16x32_bf16(ahi, bh, acc1[nt], 0, 0, 0);
      acc1[nt] = __builtin_amdgcn_mfma_f32_16x16x32_bf16(alo, bh, acc1[nt], 0, 0, 0);
      acc1[nt] = __builtin_amdgcn_mfma_f32_16x16x32_bf16(ahi, bl, acc1[nt], 0, 0, 0);
    }
  }
#pragma unroll
  for (int nt = 0; nt < 16; ++nt){
    float bv = b1[nt*16 + col];
#pragma unroll
    for (int r = 0; r < 4; ++r){
      float v = acc1[nt][r] + bv;
      v = v > 0.f ? v : 0.f;
      short h, l; split2(v, h, l);
      hidh[(wid*16 + rb + r)*264 + nt*16 + col] = (uint16_t)h;
      hidl[(wid*16 + rb + r)*264 + nt*16 + col] = (uint16_t)l;
    }
  }
  __syncthreads();

  // phase 2: out = hidden @ Wm2 + bm2, K=256, N=40 (padded to 48)
  float4v acc2[3];
#pragma unroll
  for (int nt = 0; nt < 3; ++nt){ float4v z = {0.f,0.f,0.f,0.f}; acc2[nt] = z; }
#pragma unroll
  for (int kb = 0; kb < 8; ++kb){
    int ho = (wid*16 + (lane & 15))*264 + kb*32 + ((lane >> 4) << 3);
    short8 ahi = *(const short8*)&hidh[ho];
    short8 alo = *(const short8*)&hidl[ho];
#pragma unroll
    for (int nt = 0; nt < 3; ++nt){
      short8 bh = *(const short8*)&W2hi[(kb*3 + nt)*512 + lane*8];
      short8 bl = *(const short8*)&W2lo[(kb*3 + nt)*512 + lane*8];
      acc2[nt] = __builtin_amdgcn_mfma_f32_16x16x32_bf16(ahi, bh, acc2[nt], 0, 0, 0);
      acc2[nt] = __builtin_amdgcn_mfma_f32_16x16x32_bf16(alo, bh, acc2[nt], 0, 0, 0);
      acc2[nt] = __builtin_amdgcn_mfma_f32_16x16x32_bf16(ahi, bl, acc2[nt], 0, 0, 0);
    }
  }
#pragma unroll
  for (int nt = 0; nt < 3; ++nt){
    int n = nt*16 + col;
    if (n < LL){
      float bv = b2[n];
#pragma unroll
      for (int r = 0; r < 4; ++r){
        int m = m0 + rb + r;
        if (m < M) out[(size_t)m*LL + n] = acc2[nt][r] + bv;
      }
    }
  }
}

// ---------------- launch ----------------

extern "C" void kernel_launch(void* const* d_in, const int* in_sizes, int n_in,
                              void* d_out, int out_size, void* d_ws, size_t ws_size,
                              hipStream_t stream){
  const float* x   = (const float*)d_in[0];
  const int*   ei  = (const int*)d_in[1];
  const float* W0  = (const float*)d_in[2];
  const float* b0  = (const float*)d_in[3];
  const float* W1  = (const float*)d_in[4];
  const float* b1  = (const float*)d_in[5];
  const float* W2  = (const float*)d_in[6];
  const float* b2  = (const float*)d_in[7];
  const float* Wm1 = (const float*)d_in[8];
  const float* bm1 = (const float*)d_in[9];
  const float* Wm2 = (const float*)d_in[10];
  const float* bm2 = (const float*)d_in[11];
  const int* row = ei;        // edge_index[0]
  const int* col = ei + NE;   // edge_index[1]

  char* ws = (char*)d_ws;
  size_t off = 0;
  auto alloc = [&](size_t bytes)->void*{
    void* p = ws + off;
    off += (bytes + 255) & ~(size_t)255;
    return p;
  };
  int*      counts  = (int*)alloc((size_t)NN*4);
  int*      offs    = (int*)alloc(((size_t)NN+1)*4);
  int*      cursor  = (int*)alloc((size_t)NN*4);
  int*      bsums   = (int*)alloc(1024*4);
  float*    dinv    = (float*)alloc((size_t)NN*4);
  int*      csr_col = (int*)alloc((size_t)NE*4);
  float*    csr_w   = (float*)alloc((size_t)NE*4);
  uint16_t* W0hi    = (uint16_t*)alloc(4*8*512*2);
  uint16_t* W0lo    = (uint16_t*)alloc(4*8*512*2);
  uint16_t* W1hi    = (uint16_t*)alloc(4*8*512*2);
  uint16_t* W1lo    = (uint16_t*)alloc(4*8*512*2);
  uint16_t* W2hi    = (uint16_t*)alloc(4*8*512*2);
  uint16_t* W2lo    = (uint16_t*)alloc(4*8*512*2);
  uint16_t* Wm1hi   = (uint16_t*)alloc(4*16*512*2);
  uint16_t* Wm1lo   = (uint16_t*)alloc(4*16*512*2);
  uint16_t* Wm2hi   = (uint16_t*)alloc(8*3*512*2);
  uint16_t* Wm2lo   = (uint16_t*)alloc(8*3*512*2);
  float*    HA      = (float*)alloc((size_t)NN*DD*4);
  float*    HB      = (float*)alloc((size_t)NN*DD*4);
  // total ~117 MB

  hipMemsetAsync(counts, 0, (size_t)NN*4, stream);
  count_edges<<<(NE+255)/256, 256, 0, stream>>>(row, counts);
  const int NB = (NN+255)/256;
  scan_partial<<<NB, 256, 0, stream>>>(counts, offs, bsums);
  scan_block<<<1, 512, 0, stream>>>(bsums, NB);
  scan_add<<<NB, 256, 0, stream>>>(offs, bsums, cursor);
  compute_dinv<<<(NN+255)/256, 256, 0, stream>>>(counts, dinv);
  fill_csr<<<(NE+255)/256, 256, 0, stream>>>(row, col, dinv, cursor, csr_col, csr_w);

  swz<128,128,8><<<(4*8*512+255)/256, 256, 0, stream>>>(W0, W0hi, W0lo);
  swz<128,128,8><<<(4*8*512+255)/256, 256, 0, stream>>>(W1, W1hi, W1lo);
  swz<128,128,8><<<(4*8*512+255)/256, 256, 0, stream>>>(W2, W2hi, W2lo);
  swz<128,256,16><<<(4*16*512+255)/256, 256, 0, stream>>>(Wm1, Wm1hi, Wm1lo);
  swz<256,40,3><<<(8*3*512+255)/256, 256, 0, stream>>>(Wm2, Wm2hi, Wm2lo);

  const int AGG_BLOCKS = (NN*64 + 255)/256;
  const int GB = (NN + 63)/64;

  agg_f32<<<AGG_BLOCKS, 256, 0, stream>>>((const float2*)x, offs, csr_col, csr_w, dinv, (float2*)HB);
  gemm_ip<<<GB, 256, 0, stream>>>(HB, W0hi, W0lo, b0, NN);

  agg_f32<<<AGG_BLOCKS, 256, 0, stream>>>((const float2*)HB, offs, csr_col, csr_w, dinv, (float2*)HA);
  gemm_ip<<<GB, 256, 0, stream>>>(HA, W1hi, W1lo, b1, NN);

  agg_f32<<<AGG_BLOCKS, 256, 0, stream>>>((const float2*)HA, offs, csr_col, csr_w, dinv, (float2*)HB);
  gemm_ip<<<GB, 256, 0, stream>>>(HB, W2hi, W2lo, b2, NN);

  mlp_fused<<<GB, 256, 0, stream>>>(HB, Wm1hi, Wm1lo, bm1, Wm2hi, Wm2lo, bm2, (float*)d_out, NN);
}

// Round 5
// 680.236 us; speedup vs baseline: 1.4808x; 1.2329x over previous
//
#include <hip/hip_runtime.h>
#include <hip/hip_bf16.h>
#include <stdint.h>

#define NN 100000
#define NE 1600000
#define DD 128
#define HH 256
#define LL 40

typedef __attribute__((ext_vector_type(8))) short short8;
typedef __attribute__((ext_vector_type(4))) float float4v;
typedef __attribute__((ext_vector_type(8))) float float8v;

__device__ __forceinline__ float bfu_lo(uint32_t u){ union{uint32_t i;float f;}v; v.i=u<<16; return v.f; }
__device__ __forceinline__ float bfu_hi(uint32_t u){ union{uint32_t i;float f;}v; v.i=u&0xFFFF0000u; return v.f; }
__device__ __forceinline__ float bf2f(uint16_t u){ union{uint32_t i;float f;}v; v.i=((uint32_t)u)<<16; return v.f; }
__device__ __forceinline__ uint16_t f2bf(float f){
  union{float f;uint32_t i;}v; v.f=f; uint32_t u=v.i;
  u += 0x7FFFu + ((u>>16)&1u); return (uint16_t)(u>>16);
}
// split f32 into hi+lo bf16 (lo = residual), ~16-bit effective mantissa
__device__ __forceinline__ void split2(float f, short &hi, short &lo){
  uint16_t h = f2bf(f);
  hi = (short)h;
  lo = (short)f2bf(f - bf2f(h));
}

// ---------------- preprocessing ----------------

__global__ __launch_bounds__(256) void count_edges(const int* __restrict__ row, int* __restrict__ counts){
  int e = blockIdx.x*256 + threadIdx.x;
  if (e < NE) atomicAdd(&counts[row[e]], 1);
}

__global__ __launch_bounds__(256) void scan_partial(const int* __restrict__ counts,
                                                    int* __restrict__ offs, int* __restrict__ bsums){
  __shared__ int sh[256];
  int t = threadIdx.x, i = blockIdx.x*256 + t;
  int v = (i < NN) ? counts[i] : 0;
  sh[t] = v; __syncthreads();
  for (int d = 1; d < 256; d <<= 1){
    int x = (t >= d) ? sh[t-d] : 0;
    __syncthreads();
    sh[t] += x;
    __syncthreads();
  }
  if (i < NN) offs[i] = sh[t] - v;
  if (t == 255) bsums[blockIdx.x] = sh[255];
}

__global__ __launch_bounds__(512) void scan_block(int* __restrict__ bsums, int nb){
  __shared__ int sh[512];
  int t = threadIdx.x;
  int v = (t < nb) ? bsums[t] : 0;
  sh[t] = v; __syncthreads();
  for (int d = 1; d < 512; d <<= 1){
    int x = (t >= d) ? sh[t-d] : 0;
    __syncthreads();
    sh[t] += x;
    __syncthreads();
  }
  if (t < nb) bsums[t] = sh[t] - v;
}

__global__ __launch_bounds__(256) void scan_add(int* __restrict__ offs, const int* __restrict__ bsums,
                                                int* __restrict__ cursor){
  int i = blockIdx.x*256 + threadIdx.x;
  if (i < NN){
    int v = offs[i] + bsums[blockIdx.x];
    offs[i] = v;
    cursor[i] = v;
  }
  if (i == 0) offs[NN] = NE;
}

__global__ __launch_bounds__(256) void compute_dinv(const int* __restrict__ counts, float* __restrict__ dinv){
  int i = blockIdx.x*256 + threadIdx.x;
  if (i < NN) dinv[i] = rsqrtf((float)(counts[i] + 1));
}

__global__ __launch_bounds__(256) void fill_csr(const int* __restrict__ row, const int* __restrict__ col,
                                                const float* __restrict__ dinv,
                                                int* __restrict__ cursor,
                                                int* __restrict__ csr_col, float* __restrict__ csr_w){
  int e = blockIdx.x*256 + threadIdx.x;
  if (e < NE){
    int r = row[e];
    int c = col[e];
    int p = atomicAdd(&cursor[r], 1);
    csr_col[p] = c;
    csr_w[p] = dinv[c];
  }
}

// x (f32) -> packed bf16 pairs
__global__ __launch_bounds__(256) void cvt_bf16(const float2* __restrict__ x, uint32_t* __restrict__ hb){
  int i = blockIdx.x*256 + threadIdx.x;
  if (i < NN*64){
    float2 v = x[i];
    hb[i] = (uint32_t)f2bf(v.x) | ((uint32_t)f2bf(v.y) << 16);
  }
}

// ---------------- weight pre-swizzle (f32 -> hi/lo bf16 B-fragments) ----------------

template<int KDIM, int NCOL, int NTBP>
__global__ __launch_bounds__(256) void swz(const float* __restrict__ W,
                                           uint16_t* __restrict__ Whi, uint16_t* __restrict__ Wlo){
  constexpr int KB = KDIM / 32;
  constexpr int TOT = KB * NTBP * 512;
  int idx = blockIdx.x*256 + threadIdx.x;
  if (idx >= TOT) return;
  int frag = idx >> 9, r = idx & 511, ln = r >> 3, j = r & 7;
  int kb = frag / NTBP, nt = frag - kb*NTBP;
  int k = kb*32 + ((ln >> 4) << 3) + j;
  int n = nt*16 + (ln & 15);
  float w = (n < NCOL) ? W[k*NCOL + n] : 0.f;
  short h, l; split2(w, h, l);
  Whi[idx] = (uint16_t)h; Wlo[idx] = (uint16_t)l;
}

// ---------------- aggregation: bf16 gather, f32 accumulate, 8-deep MLP ----------------
// A[r] = dinv[r] * ( sum_{c in adj(r)} dinv[c]*h[c] + dinv[r]*h[r] )   (f32 out)

__global__ __launch_bounds__(256) void agg_b(const uint32_t* __restrict__ hb,
                                             const int* __restrict__ offs,
                                             const int* __restrict__ csr_col,
                                             const float* __restrict__ csr_w,
                                             const float* __restrict__ dinv,
                                             float2* __restrict__ outp){
  const int w = (blockIdx.x*256 + threadIdx.x) >> 6;
  const int lane = threadIdx.x & 63;
  if (w >= NN) return;
  const int s = offs[w], e = offs[w+1];
  const float dr = dinv[w];
  const uint32_t us = hb[(size_t)w*64 + lane];   // self row, issued early

  float a0=0.f,a1=0.f,b0=0.f,b1=0.f,c0=0.f,c1=0.f,d0=0.f,d1=0.f;
  float e0=0.f,e1=0.f,f0=0.f,f1=0.f,g0=0.f,g1=0.f,h0=0.f,h1=0.f;
  int i = s;
  for (; i + 8 <= e; i += 8){
    int j0=csr_col[i],j1=csr_col[i+1],j2=csr_col[i+2],j3=csr_col[i+3];
    int j4=csr_col[i+4],j5=csr_col[i+5],j6=csr_col[i+6],j7=csr_col[i+7];
    float w0=csr_w[i],w1=csr_w[i+1],w2=csr_w[i+2],w3=csr_w[i+3];
    float w4=csr_w[i+4],w5=csr_w[i+5],w6=csr_w[i+6],w7=csr_w[i+7];
    uint32_t u0=hb[(size_t)j0*64+lane], u1=hb[(size_t)j1*64+lane];
    uint32_t u2=hb[(size_t)j2*64+lane], u3=hb[(size_t)j3*64+lane];
    uint32_t u4=hb[(size_t)j4*64+lane], u5=hb[(size_t)j5*64+lane];
    uint32_t u6=hb[(size_t)j6*64+lane], u7=hb[(size_t)j7*64+lane];
    a0 += w0*bfu_lo(u0); a1 += w0*bfu_hi(u0);
    b0 += w1*bfu_lo(u1); b1 += w1*bfu_hi(u1);
    c0 += w2*bfu_lo(u2); c1 += w2*bfu_hi(u2);
    d0 += w3*bfu_lo(u3); d1 += w3*bfu_hi(u3);
    e0 += w4*bfu_lo(u4); e1 += w4*bfu_hi(u4);
    f0 += w5*bfu_lo(u5); f1 += w5*bfu_hi(u5);
    g0 += w6*bfu_lo(u6); g1 += w6*bfu_hi(u6);
    h0 += w7*bfu_lo(u7); h1 += w7*bfu_hi(u7);
  }
  if (i + 4 <= e){
    int j0=csr_col[i],j1=csr_col[i+1],j2=csr_col[i+2],j3=csr_col[i+3];
    float w0=csr_w[i],w1=csr_w[i+1],w2=csr_w[i+2],w3=csr_w[i+3];
    uint32_t u0=hb[(size_t)j0*64+lane], u1=hb[(size_t)j1*64+lane];
    uint32_t u2=hb[(size_t)j2*64+lane], u3=hb[(size_t)j3*64+lane];
    a0 += w0*bfu_lo(u0); a1 += w0*bfu_hi(u0);
    b0 += w1*bfu_lo(u1); b1 += w1*bfu_hi(u1);
    c0 += w2*bfu_lo(u2); c1 += w2*bfu_hi(u2);
    d0 += w3*bfu_lo(u3); d1 += w3*bfu_hi(u3);
    i += 4;
  }
  for (; i < e; ++i){
    int c = csr_col[i]; float wt = csr_w[i];
    uint32_t u = hb[(size_t)c*64 + lane];
    a0 += wt*bfu_lo(u); a1 += wt*bfu_hi(u);
  }
  float r0 = (((a0+b0)+(c0+d0)) + ((e0+f0)+(g0+h0))) + dr*bfu_lo(us);
  float r1 = (((a1+b1)+(c1+d1)) + ((e1+f1)+(g1+h1))) + dr*bfu_hi(us);
  outp[(size_t)w*64 + lane] = make_float2(r0*dr, r1*dr);
}

// ---------------- square GEMM: H(bf16) <- relu(A(f32) @ W + b), A[M,128] ----------------
// 3-term hi/lo split on A; writes bf16.

__global__ __launch_bounds__(256) void gemm_b(const float* __restrict__ A,
                                              const uint16_t* __restrict__ Whi,
                                              const uint16_t* __restrict__ Wlo,
                                              const float* __restrict__ bias,
                                              uint16_t* __restrict__ Hout, int M){
  const int lane = threadIdx.x & 63;
  const int wid = threadIdx.x >> 6;
  const int m0 = (blockIdx.x*4 + wid)*16;
  if (m0 >= M) return;
  const int am = m0 + (lane & 15);
  const int amc = (am < M) ? am : (M - 1);

  float4v acc[8];
#pragma unroll
  for (int nt = 0; nt < 8; ++nt){ float4v z = {0.f,0.f,0.f,0.f}; acc[nt] = z; }

#pragma unroll
  for (int kb = 0; kb < 4; ++kb){
    float8v a = *(const float8v*)&A[(size_t)amc*128 + kb*32 + ((lane >> 4) << 3)];
    short8 ahi, alo;
#pragma unroll
    for (int j = 0; j < 8; ++j){ short h, l; split2(a[j], h, l); ahi[j] = h; alo[j] = l; }
#pragma unroll
    for (int nt = 0; nt < 8; ++nt){
      short8 bh = *(const short8*)&Whi[(kb*8 + nt)*512 + lane*8];
      short8 bl = *(const short8*)&Wlo[(kb*8 + nt)*512 + lane*8];
      acc[nt] = __builtin_amdgcn_mfma_f32_16x16x32_bf16(ahi, bh, acc[nt], 0, 0, 0);
      acc[nt] = __builtin_amdgcn_mfma_f32_16x16x32_bf16(alo, bh, acc[nt], 0, 0, 0);
      acc[nt] = __builtin_amdgcn_mfma_f32_16x16x32_bf16(ahi, bl, acc[nt], 0, 0, 0);
    }
  }

  const int col = lane & 15;
  const int rb  = (lane >> 4) * 4;
#pragma unroll
  for (int nt = 0; nt < 8; ++nt){
    int n = nt*16 + col;
    float bv = bias[n];
#pragma unroll
    for (int r = 0; r < 4; ++r){
      int m = m0 + rb + r;
      if (m < M){
        float v = acc[nt][r] + bv;
        Hout[(size_t)m*128 + n] = f2bf(v > 0.f ? v : 0.f);
      }
    }
  }
}

// ---------------- fused MLP: out = (relu(H @ Wm1 + bm1)) @ Wm2 + bm2, H bf16 in ----------------
// A is exact bf16 -> phase 1 needs only 2 MFMA terms (A*Whi + A*Wlo).

__global__ __launch_bounds__(256) void mlp_fused(const uint16_t* __restrict__ Hb,
                                                 const uint16_t* __restrict__ W1hi,
                                                 const uint16_t* __restrict__ W1lo,
                                                 const float* __restrict__ b1,
                                                 const uint16_t* __restrict__ W2hi,
                                                 const uint16_t* __restrict__ W2lo,
                                                 const float* __restrict__ b2,
                                                 float* __restrict__ out, int M){
  __shared__ uint16_t hidh[64*264];
  __shared__ uint16_t hidl[64*264];
  const int lane = threadIdx.x & 63;
  const int wid = threadIdx.x >> 6;
  const int m0 = (blockIdx.x*4 + wid)*16;
  const int am = m0 + (lane & 15);
  const int amc = (am < M) ? am : (M - 1);
  const int col = lane & 15;
  const int rb  = (lane >> 4) * 4;

  // phase 1: hidden = relu(H @ Wm1 + bm1), K=128, N=256
  float4v acc1[16];
#pragma unroll
  for (int nt = 0; nt < 16; ++nt){ float4v z = {0.f,0.f,0.f,0.f}; acc1[nt] = z; }
#pragma unroll
  for (int kb = 0; kb < 4; ++kb){
    short8 af = *(const short8*)&Hb[(size_t)amc*128 + kb*32 + ((lane >> 4) << 3)];
#pragma unroll
    for (int nt = 0; nt < 16; ++nt){
      short8 bh = *(const short8*)&W1hi[(kb*16 + nt)*512 + lane*8];
      short8 bl = *(const short8*)&W1lo[(kb*16 + nt)*512 + lane*8];
      acc1[nt] = __builtin_amdgcn_mfma_f32_16x16x32_bf16(af, bh, acc1[nt], 0, 0, 0);
      acc1[nt] = __builtin_amdgcn_mfma_f32_16x16x32_bf16(af, bl, acc1[nt], 0, 0, 0);
    }
  }
#pragma unroll
  for (int nt = 0; nt < 16; ++nt){
    float bv = b1[nt*16 + col];
#pragma unroll
    for (int r = 0; r < 4; ++r){
      float v = acc1[nt][r] + bv;
      v = v > 0.f ? v : 0.f;
      short h, l; split2(v, h, l);
      hidh[(wid*16 + rb + r)*264 + nt*16 + col] = (uint16_t)h;
      hidl[(wid*16 + rb + r)*264 + nt*16 + col] = (uint16_t)l;
    }
  }
  __syncthreads();

  // phase 2: out = hidden @ Wm2 + bm2, K=256, N=40 (padded to 48)
  float4v acc2[3];
#pragma unroll
  for (int nt = 0; nt < 3; ++nt){ float4v z = {0.f,0.f,0.f,0.f}; acc2[nt] = z; }
#pragma unroll
  for (int kb = 0; kb < 8; ++kb){
    int ho = (wid*16 + (lane & 15))*264 + kb*32 + ((lane >> 4) << 3);
    short8 ahi = *(const short8*)&hidh[ho];
    short8 alo = *(const short8*)&hidl[ho];
#pragma unroll
    for (int nt = 0; nt < 3; ++nt){
      short8 bh = *(const short8*)&W2hi[(kb*3 + nt)*512 + lane*8];
      short8 bl = *(const short8*)&W2lo[(kb*3 + nt)*512 + lane*8];
      acc2[nt] = __builtin_amdgcn_mfma_f32_16x16x32_bf16(ahi, bh, acc2[nt], 0, 0, 0);
      acc2[nt] = __builtin_amdgcn_mfma_f32_16x16x32_bf16(alo, bh, acc2[nt], 0, 0, 0);
      acc2[nt] = __builtin_amdgcn_mfma_f32_16x16x32_bf16(ahi, bl, acc2[nt], 0, 0, 0);
    }
  }
#pragma unroll
  for (int nt = 0; nt < 3; ++nt){
    int n = nt*16 + col;
    if (n < LL){
      float bv = b2[n];
#pragma unroll
      for (int r = 0; r < 4; ++r){
        int m = m0 + rb + r;
        if (m < M) out[(size_t)m*LL + n] = acc2[nt][r] + bv;
      }
    }
  }
}

// ---------------- launch ----------------

extern "C" void kernel_launch(void* const* d_in, const int* in_sizes, int n_in,
                              void* d_out, int out_size, void* d_ws, size_t ws_size,
                              hipStream_t stream){
  const float* x   = (const float*)d_in[0];
  const int*   ei  = (const int*)d_in[1];
  const float* W0  = (const float*)d_in[2];
  const float* b0  = (const float*)d_in[3];
  const float* W1  = (const float*)d_in[4];
  const float* b1  = (const float*)d_in[5];
  const float* W2  = (const float*)d_in[6];
  const float* b2  = (const float*)d_in[7];
  const float* Wm1 = (const float*)d_in[8];
  const float* bm1 = (const float*)d_in[9];
  const float* Wm2 = (const float*)d_in[10];
  const float* bm2 = (const float*)d_in[11];
  const int* row = ei;        // edge_index[0]
  const int* col = ei + NE;   // edge_index[1]

  char* ws = (char*)d_ws;
  size_t off = 0;
  auto alloc = [&](size_t bytes)->void*{
    void* p = ws + off;
    off += (bytes + 255) & ~(size_t)255;
    return p;
  };
  int*      counts  = (int*)alloc((size_t)NN*4);
  int*      offs    = (int*)alloc(((size_t)NN+1)*4);
  int*      cursor  = (int*)alloc((size_t)NN*4);
  int*      bsums   = (int*)alloc(1024*4);
  float*    dinv    = (float*)alloc((size_t)NN*4);
  int*      csr_col = (int*)alloc((size_t)NE*4);
  float*    csr_w   = (float*)alloc((size_t)NE*4);
  uint16_t* W0hi    = (uint16_t*)alloc(4*8*512*2);
  uint16_t* W0lo    = (uint16_t*)alloc(4*8*512*2);
  uint16_t* W1hi    = (uint16_t*)alloc(4*8*512*2);
  uint16_t* W1lo    = (uint16_t*)alloc(4*8*512*2);
  uint16_t* W2hi    = (uint16_t*)alloc(4*8*512*2);
  uint16_t* W2lo    = (uint16_t*)alloc(4*8*512*2);
  uint16_t* Wm1hi   = (uint16_t*)alloc(4*16*512*2);
  uint16_t* Wm1lo   = (uint16_t*)alloc(4*16*512*2);
  uint16_t* Wm2hi   = (uint16_t*)alloc(8*3*512*2);
  uint16_t* Wm2lo   = (uint16_t*)alloc(8*3*512*2);
  uint16_t* hb      = (uint16_t*)alloc((size_t)NN*DD*2);  // bf16 features (x, h1, h2, h3)
  float*    A       = (float*)alloc((size_t)NN*DD*4);     // f32 agg output
  // total ~99 MB

  hipMemsetAsync(counts, 0, (size_t)NN*4, stream);
  count_edges<<<(NE+255)/256, 256, 0, stream>>>(row, counts);
  const int NB = (NN+255)/256;
  scan_partial<<<NB, 256, 0, stream>>>(counts, offs, bsums);
  scan_block<<<1, 512, 0, stream>>>(bsums, NB);
  scan_add<<<NB, 256, 0, stream>>>(offs, bsums, cursor);
  compute_dinv<<<(NN+255)/256, 256, 0, stream>>>(counts, dinv);
  fill_csr<<<(NE+255)/256, 256, 0, stream>>>(row, col, dinv, cursor, csr_col, csr_w);

  swz<128,128,8><<<(4*8*512+255)/256, 256, 0, stream>>>(W0, W0hi, W0lo);
  swz<128,128,8><<<(4*8*512+255)/256, 256, 0, stream>>>(W1, W1hi, W1lo);
  swz<128,128,8><<<(4*8*512+255)/256, 256, 0, stream>>>(W2, W2hi, W2lo);
  swz<128,256,16><<<(4*16*512+255)/256, 256, 0, stream>>>(Wm1, Wm1hi, Wm1lo);
  swz<256,40,3><<<(8*3*512+255)/256, 256, 0, stream>>>(Wm2, Wm2hi, Wm2lo);

  cvt_bf16<<<(NN*64+255)/256, 256, 0, stream>>>((const float2*)x, (uint32_t*)hb);

  const int AGG_BLOCKS = (NN*64 + 255)/256;
  const int GB = (NN + 63)/64;

  agg_b<<<AGG_BLOCKS, 256, 0, stream>>>((const uint32_t*)hb, offs, csr_col, csr_w, dinv, (float2*)A);
  gemm_b<<<GB, 256, 0, stream>>>(A, W0hi, W0lo, b0, hb, NN);

  agg_b<<<AGG_BLOCKS, 256, 0, stream>>>((const uint32_t*)hb, offs, csr_col, csr_w, dinv, (float2*)A);
  gemm_b<<<GB, 256, 0, stream>>>(A, W1hi, W1lo, b1, hb, NN);

  agg_b<<<AGG_BLOCKS, 256, 0, stream>>>((const uint32_t*)hb, offs, csr_col, csr_w, dinv, (float2*)A);
  gemm_b<<<GB, 256, 0, stream>>>(A, W2hi, W2lo, b2, hb, NN);

  mlp_fused<<<GB, 256, 0, stream>>>(hb, Wm1hi, Wm1lo, bm1, Wm2hi, Wm2lo, bm2, (float*)d_out, NN);
}

// Round 6
// 598.659 us; speedup vs baseline: 1.6826x; 1.1363x over previous
//
#include <hip/hip_runtime.h>
#include <hip/hip_bf16.h>
#include <stdint.h>

#define NN 100000
#define NE 1600000
#define DD 128
#define HH 256
#define LL 40

typedef __attribute__((ext_vector_type(8))) short short8;
typedef __attribute__((ext_vector_type(4))) float float4v;
typedef __attribute__((ext_vector_type(8))) float float8v;

__device__ __forceinline__ float bfu_lo(uint32_t u){ union{uint32_t i;float f;}v; v.i=u<<16; return v.f; }
__device__ __forceinline__ float bfu_hi(uint32_t u){ union{uint32_t i;float f;}v; v.i=u&0xFFFF0000u; return v.f; }
__device__ __forceinline__ float bf2f(uint16_t u){ union{uint32_t i;float f;}v; v.i=((uint32_t)u)<<16; return v.f; }
__device__ __forceinline__ uint16_t f2bf(float f){
  union{float f;uint32_t i;}v; v.f=f; uint32_t u=v.i;
  u += 0x7FFFu + ((u>>16)&1u); return (uint16_t)(u>>16);
}
__device__ __forceinline__ void split2(float f, short &hi, short &lo){
  uint16_t h = f2bf(f);
  hi = (short)h;
  lo = (short)f2bf(f - bf2f(h));
}
__device__ __forceinline__ float u2f(uint32_t u){ union{uint32_t i;float f;}v; v.i=u; return v.f; }

// ---------------- preprocessing ----------------

// counts rows AND records each edge's rank within its row (the atomic's old value)
__global__ __launch_bounds__(256) void count_edges(const int* __restrict__ row,
                                                   int* __restrict__ counts, int* __restrict__ rank){
  int e = blockIdx.x*256 + threadIdx.x;
  if (e < NE) rank[e] = atomicAdd(&counts[row[e]], 1);
}

__global__ __launch_bounds__(256) void scan_partial(const int* __restrict__ counts,
                                                    int* __restrict__ offs, int* __restrict__ bsums){
  __shared__ int sh[256];
  int t = threadIdx.x, i = blockIdx.x*256 + t;
  int v = (i < NN) ? counts[i] : 0;
  sh[t] = v; __syncthreads();
  for (int d = 1; d < 256; d <<= 1){
    int x = (t >= d) ? sh[t-d] : 0;
    __syncthreads();
    sh[t] += x;
    __syncthreads();
  }
  if (i < NN) offs[i] = sh[t] - v;
  if (t == 255) bsums[blockIdx.x] = sh[255];
}

__global__ __launch_bounds__(512) void scan_block(int* __restrict__ bsums, int nb){
  __shared__ int sh[512];
  int t = threadIdx.x;
  int v = (t < nb) ? bsums[t] : 0;
  sh[t] = v; __syncthreads();
  for (int d = 1; d < 512; d <<= 1){
    int x = (t >= d) ? sh[t-d] : 0;
    __syncthreads();
    sh[t] += x;
    __syncthreads();
  }
  if (t < nb) bsums[t] = sh[t] - v;
}

__global__ __launch_bounds__(256) void scan_add(int* __restrict__ offs, const int* __restrict__ bsums){
  int i = blockIdx.x*256 + threadIdx.x;
  if (i < NN) offs[i] += bsums[blockIdx.x];
  if (i == 0) offs[NN] = NE;
}

__global__ __launch_bounds__(256) void compute_dinv(const int* __restrict__ counts, float* __restrict__ dinv){
  int i = blockIdx.x*256 + threadIdx.x;
  if (i < NN) dinv[i] = rsqrtf((float)(counts[i] + 1));
}

// atomic-free CSR fill: p = offs[row] + rank, one packed 8B scatter per edge
__global__ __launch_bounds__(256) void fill_csr(const int* __restrict__ row, const int* __restrict__ col,
                                                const int* __restrict__ rank,
                                                const int* __restrict__ offs,
                                                const float* __restrict__ dinv,
                                                uint2* __restrict__ csr_cw){
  int e = blockIdx.x*256 + threadIdx.x;
  if (e < NE){
    int r = row[e];
    int c = col[e];
    int p = offs[r] + rank[e];
    uint2 v;
    v.x = (uint32_t)c;
    union{float f;uint32_t i;}w; w.f = dinv[c];
    v.y = w.i;
    csr_cw[p] = v;
  }
}

// x (f32) -> packed bf16 pairs
__global__ __launch_bounds__(256) void cvt_bf16(const float2* __restrict__ x, uint32_t* __restrict__ hb){
  int i = blockIdx.x*256 + threadIdx.x;
  if (i < NN*64){
    float2 v = x[i];
    hb[i] = (uint32_t)f2bf(v.x) | ((uint32_t)f2bf(v.y) << 16);
  }
}

// ---------------- weight pre-swizzle (f32 -> hi/lo bf16 B-fragments) ----------------

template<int KDIM, int NCOL, int NTBP>
__global__ __launch_bounds__(256) void swz(const float* __restrict__ W,
                                           uint16_t* __restrict__ Whi, uint16_t* __restrict__ Wlo){
  constexpr int KB = KDIM / 32;
  constexpr int TOT = KB * NTBP * 512;
  int idx = blockIdx.x*256 + threadIdx.x;
  if (idx >= TOT) return;
  int frag = idx >> 9, r = idx & 511, ln = r >> 3, j = r & 7;
  int kb = frag / NTBP, nt = frag - kb*NTBP;
  int k = kb*32 + ((ln >> 4) << 3) + j;
  int n = nt*16 + (ln & 15);
  float w = (n < NCOL) ? W[k*NCOL + n] : 0.f;
  short h, l; split2(w, h, l);
  Whi[idx] = (uint16_t)h; Wlo[idx] = (uint16_t)l;
}

// ---------------- aggregation: bf16 gather, f32 accumulate, 8-deep MLP ----------------

__global__ __launch_bounds__(256) void agg_b(const uint32_t* __restrict__ hb,
                                             const int* __restrict__ offs,
                                             const uint2* __restrict__ csr_cw,
                                             const float* __restrict__ dinv,
                                             float2* __restrict__ outp){
  const int w = (blockIdx.x*256 + threadIdx.x) >> 6;
  const int lane = threadIdx.x & 63;
  if (w >= NN) return;
  const int s = offs[w], e = offs[w+1];
  const float dr = dinv[w];
  const uint32_t us = hb[(size_t)w*64 + lane];   // self row, issued early

  float a0=0.f,a1=0.f,b0=0.f,b1=0.f,c0=0.f,c1=0.f,d0=0.f,d1=0.f;
  float e0=0.f,e1=0.f,f0=0.f,f1=0.f,g0=0.f,g1=0.f,h0=0.f,h1=0.f;
  int i = s;
  for (; i + 8 <= e; i += 8){
    uint2 p0=csr_cw[i],  p1=csr_cw[i+1], p2=csr_cw[i+2], p3=csr_cw[i+3];
    uint2 p4=csr_cw[i+4],p5=csr_cw[i+5], p6=csr_cw[i+6], p7=csr_cw[i+7];
    uint32_t u0=hb[(size_t)p0.x*64+lane], u1=hb[(size_t)p1.x*64+lane];
    uint32_t u2=hb[(size_t)p2.x*64+lane], u3=hb[(size_t)p3.x*64+lane];
    uint32_t u4=hb[(size_t)p4.x*64+lane], u5=hb[(size_t)p5.x*64+lane];
    uint32_t u6=hb[(size_t)p6.x*64+lane], u7=hb[(size_t)p7.x*64+lane];
    a0 += u2f(p0.y)*bfu_lo(u0); a1 += u2f(p0.y)*bfu_hi(u0);
    b0 += u2f(p1.y)*bfu_lo(u1); b1 += u2f(p1.y)*bfu_hi(u1);
    c0 += u2f(p2.y)*bfu_lo(u2); c1 += u2f(p2.y)*bfu_hi(u2);
    d0 += u2f(p3.y)*bfu_lo(u3); d1 += u2f(p3.y)*bfu_hi(u3);
    e0 += u2f(p4.y)*bfu_lo(u4); e1 += u2f(p4.y)*bfu_hi(u4);
    f0 += u2f(p5.y)*bfu_lo(u5); f1 += u2f(p5.y)*bfu_hi(u5);
    g0 += u2f(p6.y)*bfu_lo(u6); g1 += u2f(p6.y)*bfu_hi(u6);
    h0 += u2f(p7.y)*bfu_lo(u7); h1 += u2f(p7.y)*bfu_hi(u7);
  }
  if (i + 4 <= e){
    uint2 p0=csr_cw[i], p1=csr_cw[i+1], p2=csr_cw[i+2], p3=csr_cw[i+3];
    uint32_t u0=hb[(size_t)p0.x*64+lane], u1=hb[(size_t)p1.x*64+lane];
    uint32_t u2=hb[(size_t)p2.x*64+lane], u3=hb[(size_t)p3.x*64+lane];
    a0 += u2f(p0.y)*bfu_lo(u0); a1 += u2f(p0.y)*bfu_hi(u0);
    b0 += u2f(p1.y)*bfu_lo(u1); b1 += u2f(p1.y)*bfu_hi(u1);
    c0 += u2f(p2.y)*bfu_lo(u2); c1 += u2f(p2.y)*bfu_hi(u2);
    d0 += u2f(p3.y)*bfu_lo(u3); d1 += u2f(p3.y)*bfu_hi(u3);
    i += 4;
  }
  for (; i < e; ++i){
    uint2 p = csr_cw[i];
    uint32_t u = hb[(size_t)p.x*64 + lane];
    a0 += u2f(p.y)*bfu_lo(u); a1 += u2f(p.y)*bfu_hi(u);
  }
  float r0 = (((a0+b0)+(c0+d0)) + ((e0+f0)+(g0+h0))) + dr*bfu_lo(us);
  float r1 = (((a1+b1)+(c1+d1)) + ((e1+f1)+(g1+h1))) + dr*bfu_hi(us);
  outp[(size_t)w*64 + lane] = make_float2(r0*dr, r1*dr);
}

// ---------------- square GEMM: H(bf16) <- relu(A(f32) @ W + b), A[M,128] ----------------

__global__ __launch_bounds__(256) void gemm_b(const float* __restrict__ A,
                                              const uint16_t* __restrict__ Whi,
                                              const uint16_t* __restrict__ Wlo,
                                              const float* __restrict__ bias,
                                              uint16_t* __restrict__ Hout, int M){
  const int lane = threadIdx.x & 63;
  const int wid = threadIdx.x >> 6;
  const int m0 = (blockIdx.x*4 + wid)*16;
  if (m0 >= M) return;
  const int am = m0 + (lane & 15);
  const int amc = (am < M) ? am : (M - 1);

  float4v acc[8];
#pragma unroll
  for (int nt = 0; nt < 8; ++nt){ float4v z = {0.f,0.f,0.f,0.f}; acc[nt] = z; }

#pragma unroll
  for (int kb = 0; kb < 4; ++kb){
    float8v a = *(const float8v*)&A[(size_t)amc*128 + kb*32 + ((lane >> 4) << 3)];
    short8 ahi, alo;
#pragma unroll
    for (int j = 0; j < 8; ++j){ short h, l; split2(a[j], h, l); ahi[j] = h; alo[j] = l; }
#pragma unroll
    for (int nt = 0; nt < 8; ++nt){
      short8 bh = *(const short8*)&Whi[(kb*8 + nt)*512 + lane*8];
      short8 bl = *(const short8*)&Wlo[(kb*8 + nt)*512 + lane*8];
      acc[nt] = __builtin_amdgcn_mfma_f32_16x16x32_bf16(ahi, bh, acc[nt], 0, 0, 0);
      acc[nt] = __builtin_amdgcn_mfma_f32_16x16x32_bf16(alo, bh, acc[nt], 0, 0, 0);
      acc[nt] = __builtin_amdgcn_mfma_f32_16x16x32_bf16(ahi, bl, acc[nt], 0, 0, 0);
    }
  }

  const int col = lane & 15;
  const int rb  = (lane >> 4) * 4;
#pragma unroll
  for (int nt = 0; nt < 8; ++nt){
    int n = nt*16 + col;
    float bv = bias[n];
#pragma unroll
    for (int r = 0; r < 4; ++r){
      int m = m0 + rb + r;
      if (m < M){
        float v = acc[nt][r] + bv;
        Hout[(size_t)m*128 + n] = f2bf(v > 0.f ? v : 0.f);
      }
    }
  }
}

// ---------------- fused MLP ----------------

__global__ __launch_bounds__(256) void mlp_fused(const uint16_t* __restrict__ Hb,
                                                 const uint16_t* __restrict__ W1hi,
                                                 const uint16_t* __restrict__ W1lo,
                                                 const float* __restrict__ b1,
                                                 const uint16_t* __restrict__ W2hi,
                                                 const uint16_t* __restrict__ W2lo,
                                                 const float* __restrict__ b2,
                                                 float* __restrict__ out, int M){
  __shared__ uint16_t hidh[64*264];
  __shared__ uint16_t hidl[64*264];
  const int lane = threadIdx.x & 63;
  const int wid = threadIdx.x >> 6;
  const int m0 = (blockIdx.x*4 + wid)*16;
  const int am = m0 + (lane & 15);
  const int amc = (am < M) ? am : (M - 1);
  const int col = lane & 15;
  const int rb  = (lane >> 4) * 4;

  float4v acc1[16];
#pragma unroll
  for (int nt = 0; nt < 16; ++nt){ float4v z = {0.f,0.f,0.f,0.f}; acc1[nt] = z; }
#pragma unroll
  for (int kb = 0; kb < 4; ++kb){
    short8 af = *(const short8*)&Hb[(size_t)amc*128 + kb*32 + ((lane >> 4) << 3)];
#pragma unroll
    for (int nt = 0; nt < 16; ++nt){
      short8 bh = *(const short8*)&W1hi[(kb*16 + nt)*512 + lane*8];
      short8 bl = *(const short8*)&W1lo[(kb*16 + nt)*512 + lane*8];
      acc1[nt] = __builtin_amdgcn_mfma_f32_16x16x32_bf16(af, bh, acc1[nt], 0, 0, 0);
      acc1[nt] = __builtin_amdgcn_mfma_f32_16x16x32_bf16(af, bl, acc1[nt], 0, 0, 0);
    }
  }
#pragma unroll
  for (int nt = 0; nt < 16; ++nt){
    float bv = b1[nt*16 + col];
#pragma unroll
    for (int r = 0; r < 4; ++r){
      float v = acc1[nt][r] + bv;
      v = v > 0.f ? v : 0.f;
      short h, l; split2(v, h, l);
      hidh[(wid*16 + rb + r)*264 + nt*16 + col] = (uint16_t)h;
      hidl[(wid*16 + rb + r)*264 + nt*16 + col] = (uint16_t)l;
    }
  }
  __syncthreads();

  float4v acc2[3];
#pragma unroll
  for (int nt = 0; nt < 3; ++nt){ float4v z = {0.f,0.f,0.f,0.f}; acc2[nt] = z; }
#pragma unroll
  for (int kb = 0; kb < 8; ++kb){
    int ho = (wid*16 + (lane & 15))*264 + kb*32 + ((lane >> 4) << 3);
    short8 ahi = *(const short8*)&hidh[ho];
    short8 alo = *(const short8*)&hidl[ho];
#pragma unroll
    for (int nt = 0; nt < 3; ++nt){
      short8 bh = *(const short8*)&W2hi[(kb*3 + nt)*512 + lane*8];
      short8 bl = *(const short8*)&W2lo[(kb*3 + nt)*512 + lane*8];
      acc2[nt] = __builtin_amdgcn_mfma_f32_16x16x32_bf16(ahi, bh, acc2[nt], 0, 0, 0);
      acc2[nt] = __builtin_amdgcn_mfma_f32_16x16x32_bf16(alo, bh, acc2[nt], 0, 0, 0);
      acc2[nt] = __builtin_amdgcn_mfma_f32_16x16x32_bf16(ahi, bl, acc2[nt], 0, 0, 0);
    }
  }
#pragma unroll
  for (int nt = 0; nt < 3; ++nt){
    int n = nt*16 + col;
    if (n < LL){
      float bv = b2[n];
#pragma unroll
      for (int r = 0; r < 4; ++r){
        int m = m0 + rb + r;
        if (m < M) out[(size_t)m*LL + n] = acc2[nt][r] + bv;
      }
    }
  }
}

// ---------------- launch ----------------

extern "C" void kernel_launch(void* const* d_in, const int* in_sizes, int n_in,
                              void* d_out, int out_size, void* d_ws, size_t ws_size,
                              hipStream_t stream){
  const float* x   = (const float*)d_in[0];
  const int*   ei  = (const int*)d_in[1];
  const float* W0  = (const float*)d_in[2];
  const float* b0  = (const float*)d_in[3];
  const float* W1  = (const float*)d_in[4];
  const float* b1  = (const float*)d_in[5];
  const float* W2  = (const float*)d_in[6];
  const float* b2  = (const float*)d_in[7];
  const float* Wm1 = (const float*)d_in[8];
  const float* bm1 = (const float*)d_in[9];
  const float* Wm2 = (const float*)d_in[10];
  const float* bm2 = (const float*)d_in[11];
  const int* row = ei;        // edge_index[0]
  const int* col = ei + NE;   // edge_index[1]

  char* ws = (char*)d_ws;
  size_t off = 0;
  auto alloc = [&](size_t bytes)->void*{
    void* p = ws + off;
    off += (bytes + 255) & ~(size_t)255;
    return p;
  };
  int*      counts  = (int*)alloc((size_t)NN*4);
  int*      offs    = (int*)alloc(((size_t)NN+1)*4);
  int*      bsums   = (int*)alloc(1024*4);
  float*    dinv    = (float*)alloc((size_t)NN*4);
  int*      rank    = (int*)alloc((size_t)NE*4);
  uint2*    csr_cw  = (uint2*)alloc((size_t)NE*8);
  uint16_t* W0hi    = (uint16_t*)alloc(4*8*512*2);
  uint16_t* W0lo    = (uint16_t*)alloc(4*8*512*2);
  uint16_t* W1hi    = (uint16_t*)alloc(4*8*512*2);
  uint16_t* W1lo    = (uint16_t*)alloc(4*8*512*2);
  uint16_t* W2hi    = (uint16_t*)alloc(4*8*512*2);
  uint16_t* W2lo    = (uint16_t*)alloc(4*8*512*2);
  uint16_t* Wm1hi   = (uint16_t*)alloc(4*16*512*2);
  uint16_t* Wm1lo   = (uint16_t*)alloc(4*16*512*2);
  uint16_t* Wm2hi   = (uint16_t*)alloc(8*3*512*2);
  uint16_t* Wm2lo   = (uint16_t*)alloc(8*3*512*2);
  uint16_t* hb      = (uint16_t*)alloc((size_t)NN*DD*2);  // bf16 features
  float*    A       = (float*)alloc((size_t)NN*DD*4);     // f32 agg output
  // total ~105 MB

  hipMemsetAsync(counts, 0, (size_t)NN*4, stream);
  count_edges<<<(NE+255)/256, 256, 0, stream>>>(row, counts, rank);
  const int NB = (NN+255)/256;
  scan_partial<<<NB, 256, 0, stream>>>(counts, offs, bsums);
  scan_block<<<1, 512, 0, stream>>>(bsums, NB);
  scan_add<<<NB, 256, 0, stream>>>(offs, bsums);
  compute_dinv<<<(NN+255)/256, 256, 0, stream>>>(counts, dinv);
  fill_csr<<<(NE+255)/256, 256, 0, stream>>>(row, col, rank, offs, dinv, csr_cw);

  swz<128,128,8><<<(4*8*512+255)/256, 256, 0, stream>>>(W0, W0hi, W0lo);
  swz<128,128,8><<<(4*8*512+255)/256, 256, 0, stream>>>(W1, W1hi, W1lo);
  swz<128,128,8><<<(4*8*512+255)/256, 256, 0, stream>>>(W2, W2hi, W2lo);
  swz<128,256,16><<<(4*16*512+255)/256, 256, 0, stream>>>(Wm1, Wm1hi, Wm1lo);
  swz<256,40,3><<<(8*3*512+255)/256, 256, 0, stream>>>(Wm2, Wm2hi, Wm2lo);

  cvt_bf16<<<(NN*64+255)/256, 256, 0, stream>>>((const float2*)x, (uint32_t*)hb);

  const int AGG_BLOCKS = (NN*64 + 255)/256;
  const int GB = (NN + 63)/64;

  agg_b<<<AGG_BLOCKS, 256, 0, stream>>>((const uint32_t*)hb, offs, csr_cw, dinv, (float2*)A);
  gemm_b<<<GB, 256, 0, stream>>>(A, W0hi, W0lo, b0, hb, NN);

  agg_b<<<AGG_BLOCKS, 256, 0, stream>>>((const uint32_t*)hb, offs, csr_cw, dinv, (float2*)A);
  gemm_b<<<GB, 256, 0, stream>>>(A, W1hi, W1lo, b1, hb, NN);

  agg_b<<<AGG_BLOCKS, 256, 0, stream>>>((const uint32_t*)hb, offs, csr_cw, dinv, (float2*)A);
  gemm_b<<<GB, 256, 0, stream>>>(A, W2hi, W2lo, b2, hb, NN);

  mlp_fused<<<GB, 256, 0, stream>>>(hb, Wm1hi, Wm1lo, bm1, Wm2hi, Wm2lo, bm2, (float*)d_out, NN);
}

// Round 7
// 590.818 us; speedup vs baseline: 1.7049x; 1.0133x over previous
//
#include <hip/hip_runtime.h>
#include <hip/hip_bf16.h>
#include <stdint.h>

#define NN 100000
#define NE 1600000
#define DD 128
#define HH 256
#define LL 40

typedef __attribute__((ext_vector_type(8))) short short8;
typedef __attribute__((ext_vector_type(4))) float float4v;
typedef __attribute__((ext_vector_type(8))) float float8v;

__device__ __forceinline__ float bfu_lo(uint32_t u){ union{uint32_t i;float f;}v; v.i=u<<16; return v.f; }
__device__ __forceinline__ float bfu_hi(uint32_t u){ union{uint32_t i;float f;}v; v.i=u&0xFFFF0000u; return v.f; }
__device__ __forceinline__ float bf2f(uint16_t u){ union{uint32_t i;float f;}v; v.i=((uint32_t)u)<<16; return v.f; }
__device__ __forceinline__ uint16_t f2bf(float f){
  union{float f;uint32_t i;}v; v.f=f; uint32_t u=v.i;
  u += 0x7FFFu + ((u>>16)&1u); return (uint16_t)(u>>16);
}
__device__ __forceinline__ void split2(float f, short &hi, short &lo){
  uint16_t h = f2bf(f);
  hi = (short)h;
  lo = (short)f2bf(f - bf2f(h));
}
__device__ __forceinline__ float u2f(uint32_t u){ union{uint32_t i;float f;}v; v.i=u; return v.f; }

// ---------------- preprocessing ----------------

__global__ __launch_bounds__(256) void count_edges(const int* __restrict__ row,
                                                   int* __restrict__ counts, int* __restrict__ rank){
  int e = blockIdx.x*256 + threadIdx.x;
  if (e < NE) rank[e] = atomicAdd(&counts[row[e]], 1);
}

__global__ __launch_bounds__(256) void scan_partial(const int* __restrict__ counts,
                                                    int* __restrict__ offs, int* __restrict__ bsums){
  __shared__ int sh[256];
  int t = threadIdx.x, i = blockIdx.x*256 + t;
  int v = (i < NN) ? counts[i] : 0;
  sh[t] = v; __syncthreads();
  for (int d = 1; d < 256; d <<= 1){
    int x = (t >= d) ? sh[t-d] : 0;
    __syncthreads();
    sh[t] += x;
    __syncthreads();
  }
  if (i < NN) offs[i] = sh[t] - v;
  if (t == 255) bsums[blockIdx.x] = sh[255];
}

__global__ __launch_bounds__(512) void scan_block(int* __restrict__ bsums, int nb){
  __shared__ int sh[512];
  int t = threadIdx.x;
  int v = (t < nb) ? bsums[t] : 0;
  sh[t] = v; __syncthreads();
  for (int d = 1; d < 512; d <<= 1){
    int x = (t >= d) ? sh[t-d] : 0;
    __syncthreads();
    sh[t] += x;
    __syncthreads();
  }
  if (t < nb) bsums[t] = sh[t] - v;
}

__global__ __launch_bounds__(256) void scan_add(int* __restrict__ offs, const int* __restrict__ bsums){
  int i = blockIdx.x*256 + threadIdx.x;
  if (i < NN) offs[i] += bsums[blockIdx.x];
  if (i == 0) offs[NN] = NE;
}

__global__ __launch_bounds__(256) void compute_dinv(const int* __restrict__ counts, float* __restrict__ dinv){
  int i = blockIdx.x*256 + threadIdx.x;
  if (i < NN) dinv[i] = rsqrtf((float)(counts[i] + 1));
}

__global__ __launch_bounds__(256) void fill_csr(const int* __restrict__ row, const int* __restrict__ col,
                                                const int* __restrict__ rank,
                                                const int* __restrict__ offs,
                                                const float* __restrict__ dinv,
                                                uint2* __restrict__ csr_cw){
  int e = blockIdx.x*256 + threadIdx.x;
  if (e < NE){
    int r = row[e];
    int c = col[e];
    int p = offs[r] + rank[e];
    uint2 v;
    v.x = (uint32_t)c;
    union{float f;uint32_t i;}w; w.f = dinv[c];
    v.y = w.i;
    csr_cw[p] = v;
  }
}

__global__ __launch_bounds__(256) void cvt_bf16(const float2* __restrict__ x, uint32_t* __restrict__ hb){
  int i = blockIdx.x*256 + threadIdx.x;
  if (i < NN*64){
    float2 v = x[i];
    hb[i] = (uint32_t)f2bf(v.x) | ((uint32_t)f2bf(v.y) << 16);
  }
}

// ---------------- weight pre-swizzle (f32 -> hi/lo bf16 B-fragments) ----------------

template<int KDIM, int NCOL, int NTBP>
__global__ __launch_bounds__(256) void swz(const float* __restrict__ W,
                                           uint16_t* __restrict__ Whi, uint16_t* __restrict__ Wlo){
  constexpr int KB = KDIM / 32;
  constexpr int TOT = KB * NTBP * 512;
  int idx = blockIdx.x*256 + threadIdx.x;
  if (idx >= TOT) return;
  int frag = idx >> 9, r = idx & 511, ln = r >> 3, j = r & 7;
  int kb = frag / NTBP, nt = frag - kb*NTBP;
  int k = kb*32 + ((ln >> 4) << 3) + j;
  int n = nt*16 + (ln & 15);
  float w = (n < NCOL) ? W[k*NCOL + n] : 0.f;
  short h, l; split2(w, h, l);
  Whi[idx] = (uint16_t)h; Wlo[idx] = (uint16_t)l;
}

// ---------------- aggregation: bf16 gather, f32 accumulate, 8-deep MLP ----------------

__global__ __launch_bounds__(256) void agg_b(const uint32_t* __restrict__ hb,
                                             const int* __restrict__ offs,
                                             const uint2* __restrict__ csr_cw,
                                             const float* __restrict__ dinv,
                                             float2* __restrict__ outp){
  const int w = (blockIdx.x*256 + threadIdx.x) >> 6;
  const int lane = threadIdx.x & 63;
  if (w >= NN) return;
  const int s = offs[w], e = offs[w+1];
  const float dr = dinv[w];
  const uint32_t us = hb[(size_t)w*64 + lane];

  float a0=0.f,a1=0.f,b0=0.f,b1=0.f,c0=0.f,c1=0.f,d0=0.f,d1=0.f;
  float e0=0.f,e1=0.f,f0=0.f,f1=0.f,g0=0.f,g1=0.f,h0=0.f,h1=0.f;
  int i = s;
  for (; i + 8 <= e; i += 8){
    uint2 p0=csr_cw[i],  p1=csr_cw[i+1], p2=csr_cw[i+2], p3=csr_cw[i+3];
    uint2 p4=csr_cw[i+4],p5=csr_cw[i+5], p6=csr_cw[i+6], p7=csr_cw[i+7];
    uint32_t u0=hb[(size_t)p0.x*64+lane], u1=hb[(size_t)p1.x*64+lane];
    uint32_t u2=hb[(size_t)p2.x*64+lane], u3=hb[(size_t)p3.x*64+lane];
    uint32_t u4=hb[(size_t)p4.x*64+lane], u5=hb[(size_t)p5.x*64+lane];
    uint32_t u6=hb[(size_t)p6.x*64+lane], u7=hb[(size_t)p7.x*64+lane];
    a0 += u2f(p0.y)*bfu_lo(u0); a1 += u2f(p0.y)*bfu_hi(u0);
    b0 += u2f(p1.y)*bfu_lo(u1); b1 += u2f(p1.y)*bfu_hi(u1);
    c0 += u2f(p2.y)*bfu_lo(u2); c1 += u2f(p2.y)*bfu_hi(u2);
    d0 += u2f(p3.y)*bfu_lo(u3); d1 += u2f(p3.y)*bfu_hi(u3);
    e0 += u2f(p4.y)*bfu_lo(u4); e1 += u2f(p4.y)*bfu_hi(u4);
    f0 += u2f(p5.y)*bfu_lo(u5); f1 += u2f(p5.y)*bfu_hi(u5);
    g0 += u2f(p6.y)*bfu_lo(u6); g1 += u2f(p6.y)*bfu_hi(u6);
    h0 += u2f(p7.y)*bfu_lo(u7); h1 += u2f(p7.y)*bfu_hi(u7);
  }
  if (i + 4 <= e){
    uint2 p0=csr_cw[i], p1=csr_cw[i+1], p2=csr_cw[i+2], p3=csr_cw[i+3];
    uint32_t u0=hb[(size_t)p0.x*64+lane], u1=hb[(size_t)p1.x*64+lane];
    uint32_t u2=hb[(size_t)p2.x*64+lane], u3=hb[(size_t)p3.x*64+lane];
    a0 += u2f(p0.y)*bfu_lo(u0); a1 += u2f(p0.y)*bfu_hi(u0);
    b0 += u2f(p1.y)*bfu_lo(u1); b1 += u2f(p1.y)*bfu_hi(u1);
    c0 += u2f(p2.y)*bfu_lo(u2); c1 += u2f(p2.y)*bfu_hi(u2);
    d0 += u2f(p3.y)*bfu_lo(u3); d1 += u2f(p3.y)*bfu_hi(u3);
    i += 4;
  }
  for (; i < e; ++i){
    uint2 p = csr_cw[i];
    uint32_t u = hb[(size_t)p.x*64 + lane];
    a0 += u2f(p.y)*bfu_lo(u); a1 += u2f(p.y)*bfu_hi(u);
  }
  float r0 = (((a0+b0)+(c0+d0)) + ((e0+f0)+(g0+h0))) + dr*bfu_lo(us);
  float r1 = (((a1+b1)+(c1+d1)) + ((e1+f1)+(g1+h1))) + dr*bfu_hi(us);
  outp[(size_t)w*64 + lane] = make_float2(r0*dr, r1*dr);
}

// ---------------- square GEMM: H(bf16) <- relu(A(f32) @ W + b), A[M,128] ----------------

__global__ __launch_bounds__(256) void gemm_b(const float* __restrict__ A,
                                              const uint16_t* __restrict__ Whi,
                                              const uint16_t* __restrict__ Wlo,
                                              const float* __restrict__ bias,
                                              uint16_t* __restrict__ Hout, int M){
  const int lane = threadIdx.x & 63;
  const int wid = threadIdx.x >> 6;
  const int m0 = (blockIdx.x*4 + wid)*16;
  if (m0 >= M) return;
  const int am = m0 + (lane & 15);
  const int amc = (am < M) ? am : (M - 1);

  float4v acc[8];
#pragma unroll
  for (int nt = 0; nt < 8; ++nt){ float4v z = {0.f,0.f,0.f,0.f}; acc[nt] = z; }

#pragma unroll
  for (int kb = 0; kb < 4; ++kb){
    float8v a = *(const float8v*)&A[(size_t)amc*128 + kb*32 + ((lane >> 4) << 3)];
    short8 ahi, alo;
#pragma unroll
    for (int j = 0; j < 8; ++j){ short h, l; split2(a[j], h, l); ahi[j] = h; alo[j] = l; }
#pragma unroll
    for (int nt = 0; nt < 8; ++nt){
      short8 bh = *(const short8*)&Whi[(kb*8 + nt)*512 + lane*8];
      short8 bl = *(const short8*)&Wlo[(kb*8 + nt)*512 + lane*8];
      acc[nt] = __builtin_amdgcn_mfma_f32_16x16x32_bf16(ahi, bh, acc[nt], 0, 0, 0);
      acc[nt] = __builtin_amdgcn_mfma_f32_16x16x32_bf16(alo, bh, acc[nt], 0, 0, 0);
      acc[nt] = __builtin_amdgcn_mfma_f32_16x16x32_bf16(ahi, bl, acc[nt], 0, 0, 0);
    }
  }

  const int col = lane & 15;
  const int rb  = (lane >> 4) * 4;
#pragma unroll
  for (int nt = 0; nt < 8; ++nt){
    int n = nt*16 + col;
    float bv = bias[n];
#pragma unroll
    for (int r = 0; r < 4; ++r){
      int m = m0 + rb + r;
      if (m < M){
        float v = acc[nt][r] + bv;
        Hout[(size_t)m*128 + n] = f2bf(v > 0.f ? v : 0.f);
      }
    }
  }
}

// ---------------- fused MLP: hidden tile plain bf16 in LDS, stride 260 ----------------
// stride 260 uint16: quad store bank base = (2*4q*260)%32 = 8q -> disjoint octets,
// phase-1 stores conflict-free; 33.3 KB LDS -> 4 blocks/CU.

#define HS 260

__global__ __launch_bounds__(256) void mlp_fused(const uint16_t* __restrict__ Hb,
                                                 const uint16_t* __restrict__ W1hi,
                                                 const uint16_t* __restrict__ W1lo,
                                                 const float* __restrict__ b1,
                                                 const uint16_t* __restrict__ W2hi,
                                                 const uint16_t* __restrict__ W2lo,
                                                 const float* __restrict__ b2,
                                                 float* __restrict__ out, int M){
  __shared__ uint16_t hid[64*HS];
  const int lane = threadIdx.x & 63;
  const int wid = threadIdx.x >> 6;
  const int m0 = (blockIdx.x*4 + wid)*16;
  const int am = m0 + (lane & 15);
  const int amc = (am < M) ? am : (M - 1);
  const int col = lane & 15;
  const int rb  = (lane >> 4) * 4;

  // phase 1: hidden = relu(Hb @ Wm1 + bm1), K=128, N=256
  float4v acc1[16];
#pragma unroll
  for (int nt = 0; nt < 16; ++nt){ float4v z = {0.f,0.f,0.f,0.f}; acc1[nt] = z; }
#pragma unroll
  for (int kb = 0; kb < 4; ++kb){
    short8 af = *(const short8*)&Hb[(size_t)amc*128 + kb*32 + ((lane >> 4) << 3)];
#pragma unroll
    for (int nt = 0; nt < 16; ++nt){
      short8 bh = *(const short8*)&W1hi[(kb*16 + nt)*512 + lane*8];
      short8 bl = *(const short8*)&W1lo[(kb*16 + nt)*512 + lane*8];
      acc1[nt] = __builtin_amdgcn_mfma_f32_16x16x32_bf16(af, bh, acc1[nt], 0, 0, 0);
      acc1[nt] = __builtin_amdgcn_mfma_f32_16x16x32_bf16(af, bl, acc1[nt], 0, 0, 0);
    }
  }
#pragma unroll
  for (int nt = 0; nt < 16; ++nt){
    float bv = b1[nt*16 + col];
#pragma unroll
    for (int r = 0; r < 4; ++r){
      float v = acc1[nt][r] + bv;
      v = v > 0.f ? v : 0.f;
      hid[(wid*16 + rb + r)*HS + nt*16 + col] = f2bf(v);
    }
  }
  __syncthreads();

  // phase 2: out = hidden @ Wm2 + bm2, K=256, N=40 (padded to 48), 2-term
  float4v acc2[3];
#pragma unroll
  for (int nt = 0; nt < 3; ++nt){ float4v z = {0.f,0.f,0.f,0.f}; acc2[nt] = z; }
#pragma unroll
  for (int kb = 0; kb < 8; ++kb){
    int ho = (wid*16 + (lane & 15))*HS + kb*32 + ((lane >> 4) << 3);
    short8 af = *(const short8*)&hid[ho];
#pragma unroll
    for (int nt = 0; nt < 3; ++nt){
      short8 bh = *(const short8*)&W2hi[(kb*3 + nt)*512 + lane*8];
      short8 bl = *(const short8*)&W2lo[(kb*3 + nt)*512 + lane*8];
      acc2[nt] = __builtin_amdgcn_mfma_f32_16x16x32_bf16(af, bh, acc2[nt], 0, 0, 0);
      acc2[nt] = __builtin_amdgcn_mfma_f32_16x16x32_bf16(af, bl, acc2[nt], 0, 0, 0);
    }
  }
#pragma unroll
  for (int nt = 0; nt < 3; ++nt){
    int n = nt*16 + col;
    if (n < LL){
      float bv = b2[n];
#pragma unroll
      for (int r = 0; r < 4; ++r){
        int m = m0 + rb + r;
        if (m < M) out[(size_t)m*LL + n] = acc2[nt][r] + bv;
      }
    }
  }
}

// ---------------- launch ----------------

extern "C" void kernel_launch(void* const* d_in, const int* in_sizes, int n_in,
                              void* d_out, int out_size, void* d_ws, size_t ws_size,
                              hipStream_t stream){
  const float* x   = (const float*)d_in[0];
  const int*   ei  = (const int*)d_in[1];
  const float* W0  = (const float*)d_in[2];
  const float* b0  = (const float*)d_in[3];
  const float* W1  = (const float*)d_in[4];
  const float* b1  = (const float*)d_in[5];
  const float* W2  = (const float*)d_in[6];
  const float* b2  = (const float*)d_in[7];
  const float* Wm1 = (const float*)d_in[8];
  const float* bm1 = (const float*)d_in[9];
  const float* Wm2 = (const float*)d_in[10];
  const float* bm2 = (const float*)d_in[11];
  const int* row = ei;
  const int* col = ei + NE;

  char* ws = (char*)d_ws;
  size_t off = 0;
  auto alloc = [&](size_t bytes)->void*{
    void* p = ws + off;
    off += (bytes + 255) & ~(size_t)255;
    return p;
  };
  int*      counts  = (int*)alloc((size_t)NN*4);
  int*      offs    = (int*)alloc(((size_t)NN+1)*4);
  int*      bsums   = (int*)alloc(1024*4);
  float*    dinv    = (float*)alloc((size_t)NN*4);
  int*      rank    = (int*)alloc((size_t)NE*4);
  uint2*    csr_cw  = (uint2*)alloc((size_t)NE*8);
  uint16_t* W0hi    = (uint16_t*)alloc(4*8*512*2);
  uint16_t* W0lo    = (uint16_t*)alloc(4*8*512*2);
  uint16_t* W1hi    = (uint16_t*)alloc(4*8*512*2);
  uint16_t* W1lo    = (uint16_t*)alloc(4*8*512*2);
  uint16_t* W2hi    = (uint16_t*)alloc(4*8*512*2);
  uint16_t* W2lo    = (uint16_t*)alloc(4*8*512*2);
  uint16_t* Wm1hi   = (uint16_t*)alloc(4*16*512*2);
  uint16_t* Wm1lo   = (uint16_t*)alloc(4*16*512*2);
  uint16_t* Wm2hi   = (uint16_t*)alloc(8*3*512*2);
  uint16_t* Wm2lo   = (uint16_t*)alloc(8*3*512*2);
  uint16_t* hb      = (uint16_t*)alloc((size_t)NN*DD*2);
  float*    A       = (float*)alloc((size_t)NN*DD*4);

  hipMemsetAsync(counts, 0, (size_t)NN*4, stream);
  count_edges<<<(NE+255)/256, 256, 0, stream>>>(row, counts, rank);
  const int NB = (NN+255)/256;
  scan_partial<<<NB, 256, 0, stream>>>(counts, offs, bsums);
  scan_block<<<1, 512, 0, stream>>>(bsums, NB);
  scan_add<<<NB, 256, 0, stream>>>(offs, bsums);
  compute_dinv<<<(NN+255)/256, 256, 0, stream>>>(counts, dinv);
  fill_csr<<<(NE+255)/256, 256, 0, stream>>>(row, col, rank, offs, dinv, csr_cw);

  swz<128,128,8><<<(4*8*512+255)/256, 256, 0, stream>>>(W0, W0hi, W0lo);
  swz<128,128,8><<<(4*8*512+255)/256, 256, 0, stream>>>(W1, W1hi, W1lo);
  swz<128,128,8><<<(4*8*512+255)/256, 256, 0, stream>>>(W2, W2hi, W2lo);
  swz<128,256,16><<<(4*16*512+255)/256, 256, 0, stream>>>(Wm1, Wm1hi, Wm1lo);
  swz<256,40,3><<<(8*3*512+255)/256, 256, 0, stream>>>(Wm2, Wm2hi, Wm2lo);

  cvt_bf16<<<(NN*64+255)/256, 256, 0, stream>>>((const float2*)x, (uint32_t*)hb);

  const int AGG_BLOCKS = (NN*64 + 255)/256;
  const int GB = (NN + 63)/64;

  agg_b<<<AGG_BLOCKS, 256, 0, stream>>>((const uint32_t*)hb, offs, csr_cw, dinv, (float2*)A);
  gemm_b<<<GB, 256, 0, stream>>>(A, W0hi, W0lo, b0, hb, NN);

  agg_b<<<AGG_BLOCKS, 256, 0, stream>>>((const uint32_t*)hb, offs, csr_cw, dinv, (float2*)A);
  gemm_b<<<GB, 256, 0, stream>>>(A, W1hi, W1lo, b1, hb, NN);

  agg_b<<<AGG_BLOCKS, 256, 0, stream>>>((const uint32_t*)hb, offs, csr_cw, dinv, (float2*)A);
  gemm_b<<<GB, 256, 0, stream>>>(A, W2hi, W2lo, b2, hb, NN);

  mlp_fused<<<GB, 256, 0, stream>>>(hb, Wm1hi, Wm1lo, bm1, Wm2hi, Wm2lo, bm2, (float*)d_out, NN);
}